// Round 5
// baseline (858.960 us; speedup 1.0000x reference)
//
#include <hip/hip_runtime.h>

#define DI __device__ __forceinline__

typedef short bfrag8 __attribute__((ext_vector_type(8)));
typedef float ffrag4 __attribute__((ext_vector_type(4)));

DI ushort f2b(float f){
  union { float f; unsigned u; } v; v.f = f;
  unsigned u = v.u;
  u += 0x7FFF + ((u >> 16) & 1);   // round-to-nearest-even
  return (ushort)(u >> 16);
}
DI float b2f(ushort h){
  union { unsigned u; float f; } v; v.u = ((unsigned)h) << 16;
  return v.f;
}
DI float sigm(float x){ return 1.0f / (1.0f + __expf(-x)); }
DI float tanh_(float x){ return 1.0f - 2.0f / (1.0f + __expf(2.0f * x)); }
DI float elu_(float x){ return x > 0.f ? x : __expf(x) - 1.f; }

// ---------------------------------------------------------------------------
// Attention probs for a pair of GAT layers from sample 0 AND build the fused
// linear-operator MFMA B-frags for both layers. 1 block x 576 threads.
// M[(j*Cin+k),(i*Cout+o)] = p[h(o),i,j]*W[k,o].  Frag layout [nt][kt][64][8].
// ---------------------------------------------------------------------------
__global__ void k_probs(const float* xf, const ushort* xb, int in_c,
                        const float* W1, const float* b1, const float* a1, int hc1, int c1,
                        const float* W2, const float* b2, const float* a2, int hc2, int c2,
                        ushort* __restrict__ M1dst, int KT1,
                        ushort* __restrict__ M2dst, int KT2)
{
  __shared__ float xs[12 * 22];
  __shared__ float h1[12 * 16];
  __shared__ float lg[576];
  __shared__ float prA[576];
  __shared__ float prB[576];
  __shared__ float h1e[12 * 16];
  __shared__ float h2[12 * 24];
  const int t = threadIdx.x;
  const unsigned adj[12] = {0xC21u,0x482u,0x844u,0x048u,0x030u,0x031u,
                            0x44Cu,0x282u,0xF00u,0x780u,0xF43u,0xD05u};
  if (t < 12 * in_c){
    if (xf) xs[t] = xf[t];
    else    xs[t] = b2f(xb[t]);
  }
  __syncthreads();
  if (t < 12 * hc1){
    int i = t / hc1, o = t % hc1;
    float v = b1[o];
    for (int k = 0; k < in_c; k++) v += xs[i * in_c + k] * W1[k * hc1 + o];
    h1[t] = v;
  }
  __syncthreads();
  {
    int h = t / 144, ij = t % 144, i = ij / 12, j = ij % 12;
    float v;
    if ((adj[i] >> j) & 1){
      v = 0.f;
      for (int c = 0; c < c1; c++)
        v += a1[h*2*c1 + c] * h1[i*hc1 + h*c1 + c] + a1[h*2*c1 + c1 + c] * h1[j*hc1 + h*c1 + c];
      v = v > 0.f ? v : 0.2f * v;
    } else v = -9e15f;
    lg[t] = v;
  }
  __syncthreads();
  if (t < 48){
    int h = t / 12, i = t % 12;
    const float* row = &lg[h*144 + i*12];
    float m = row[0];
    for (int j = 1; j < 12; j++) m = fmaxf(m, row[j]);
    float e[12], s = 0.f;
    for (int j = 0; j < 12; j++){ e[j] = __expf(row[j] - m); s += e[j]; }
    float inv = 1.f / s;
    for (int j = 0; j < 12; j++) prA[h*144 + i*12 + j] = e[j] * inv;
  }
  __syncthreads();
  if (t < 12 * hc1){
    int i = t / hc1, o = t % hc1, h = o / c1;
    float v = 0.f;
    for (int j = 0; j < 12; j++) v += prA[h*144 + i*12 + j] * h1[j*hc1 + o];
    h1e[t] = elu_(v);
  }
  __syncthreads();
  if (t < 12 * hc2){
    int i = t / hc2, o = t % hc2;
    float v = b2[o];
    for (int k = 0; k < hc1; k++) v += h1e[i*hc1 + k] * W2[k*hc2 + o];
    h2[t] = v;
  }
  __syncthreads();
  {
    int h = t / 144, ij = t % 144, i = ij / 12, j = ij % 12;
    float v;
    if ((adj[i] >> j) & 1){
      v = 0.f;
      for (int c = 0; c < c2; c++)
        v += a2[h*2*c2 + c] * h2[i*hc2 + h*c2 + c] + a2[h*2*c2 + c2 + c] * h2[j*hc2 + h*c2 + c];
      v = v > 0.f ? v : 0.2f * v;
    } else v = -9e15f;
    lg[t] = v;
  }
  __syncthreads();
  if (t < 48){
    int h = t / 12, i = t % 12;
    const float* row = &lg[h*144 + i*12];
    float m = row[0];
    for (int j = 1; j < 12; j++) m = fmaxf(m, row[j]);
    float e[12], s = 0.f;
    for (int j = 0; j < 12; j++){ e[j] = __expf(row[j] - m); s += e[j]; }
    float inv = 1.f / s;
    for (int j = 0; j < 12; j++) prB[h*144 + i*12 + j] = e[j] * inv;
  }
  __syncthreads();
  // ---- build fused-operator frags, layer 1 (prA, W1) ----
  {
    int NT = (12 * hc1) / 16, K = 12 * in_c;
    for (int idx = t; idx < NT * KT1 * 64; idx += 576){
      int bI = idx >> 6, li = idx & 63;
      int kt = bI % KT1, nt = bI / KT1;
      int n = nt * 16 + (li & 15);
      int i = n / hc1, o = n % hc1;
      union { ushort u[8]; uint4 v; } pk;
      #pragma unroll
      for (int j = 0; j < 8; j++){
        int k = kt * 32 + (li >> 4) * 8 + j;
        float v = 0.f;
        if (k < K){
          int jj = k / in_c, kk = k % in_c;
          v = prA[(o / c1) * 144 + i * 12 + jj] * W1[kk * hc1 + o];
        }
        pk.u[j] = f2b(v);
      }
      *(uint4*)&M1dst[(long)idx * 8] = pk.v;
    }
  }
  // ---- layer 2 (prB, W2) ----
  {
    int NT = (12 * hc2) / 16, K = 12 * hc1;
    for (int idx = t; idx < NT * KT2 * 64; idx += 576){
      int bI = idx >> 6, li = idx & 63;
      int kt = bI % KT2, nt = bI / KT2;
      int n = nt * 16 + (li & 15);
      int i = n / hc2, o = n % hc2;
      union { ushort u[8]; uint4 v; } pk;
      #pragma unroll
      for (int j = 0; j < 8; j++){
        int k = kt * 32 + (li >> 4) * 8 + j;
        float v = 0.f;
        if (k < K){
          int jj = k / hc1, kk = k % hc1;
          v = prB[(o / c2) * 144 + i * 12 + jj] * W2[kk * hc2 + o];
        }
        pk.u[j] = f2b(v);
      }
      *(uint4*)&M2dst[(long)idx * 8] = pk.v;
    }
  }
}

// ---------------------------------------------------------------------------
// Prep LSTM weights (y=0..3) and fW (y=4) into frag layouts. grid (360,5)x64.
// LSTM: task tau<36 -> Whh tile (gt=tau/9,ct=tau%9), tau>=36 -> Wih tile.
// ---------------------------------------------------------------------------
__global__ void k_prep_all(const float* eWih0, const float* eWhh0,
                           const float* eWih1, const float* eWhh1,
                           const float* dWhh0,
                           const float* dWih1, const float* dWhh1,
                           const float* fW,
                           ushort* __restrict__ lstmF, ushort* __restrict__ fWt)
{
  int y = blockIdx.y;
  int l = threadIdx.x, ln = l & 15, q = l >> 4;
  if (y == 4){
    int bI = blockIdx.x;
    if (bI >= 153) return;
    int nt = bI / 9, kt = bI % 9;
    int n = nt * 16 + ln;
    union { ushort u[8]; uint4 v; } pk;
    #pragma unroll
    for (int j = 0; j < 8; j++){
      int k = kt * 32 + q * 8 + j;
      float v = (k < 288 && n < 264) ? fW[k * 264 + n] : 0.f;
      pk.u[j] = f2b(v);
    }
    *(uint4*)&fWt[((long)(bI * 64 + l)) * 8] = pk.v;
    return;
  }
  const float* Wh; const float* Wx; long off; int ntau;
  if (y == 0){ Wh = eWhh0; Wx = eWih0; off = 0;      ntau = 72; }
  else if (y == 1){ Wh = eWhh1; Wx = eWih1; off = 184320; ntau = 72; }
  else if (y == 2){ Wh = dWhh0; Wx = dWhh0; off = 368640; ntau = 36; }
  else { Wh = dWhh1; Wx = dWih1; off = 460800; ntau = 72; }
  int bI = blockIdx.x;                 // tau*5 + kt
  int tau = bI / 5, kt = bI % 5;
  if (tau >= ntau) return;
  const float* W = (tau < 36) ? Wh : Wx;
  int tt = (tau < 36) ? tau : tau - 36;
  int gt = tt / 9, ct = tt % 9;
  int n = gt * 144 + ct * 16 + ln;
  ushort* d = lstmF + off;
  union { ushort u[8]; uint4 v; } pk;
  #pragma unroll
  for (int j = 0; j < 8; j++){
    int k = kt * 32 + q * 8 + j;
    float v = (k < 144) ? W[(long)n * 144 + k] : 0.f;
    pk.u[j] = f2b(v);
  }
  *(uint4*)&d[((long)(bI * 64 + l)) * 8] = pk.v;
}

// ---------------------------------------------------------------------------
// GAT layers 0+1 as fused-operator MFMA GEMMs. 512 thr, 64 rows/block,
// grid 1536, ~63 KB LDS -> 2 blocks/CU. Conflict-free strides (296, 200).
// ---------------------------------------------------------------------------
__global__ __launch_bounds__(512) void k_gat01(
    const float* __restrict__ x, const ushort* __restrict__ M0f, const float* __restrict__ b0,
    const ushort* __restrict__ M1f, const float* __restrict__ b1,
    ushort* __restrict__ seq)
{
  __shared__ ushort xs[64 * 296];     // 37888 B (K pad 264->296; reused for out stride 144)
  __shared__ ushort h1e[64 * 200];    // 25600 B
  int t = threadIdx.x;
  long row0 = (long)blockIdx.x * 64;
  int w = t >> 6, l = t & 63, q = l >> 4, ln = l & 15;
  if (t < 256){
    int row = t >> 2, seg = t & 3;
    *(uint4*)&xs[row * 296 + 264 + seg * 8] = make_uint4(0u, 0u, 0u, 0u);
  }
  for (int idx = t; idx < 4224; idx += 512){
    int row = idx / 66, c4 = idx % 66;
    float4 v = *(const float4*)&x[(row0 + row) * 264 + c4 * 4];
    ushort4 o; o.x = f2b(v.x); o.y = f2b(v.y); o.z = f2b(v.z); o.w = f2b(v.w);
    *(ushort4*)&xs[row * 296 + c4 * 4] = o;
  }
  int nta[2] = {w, (w < 4) ? 8 + w : -1};
  bfrag8 f0[2][9];
  #pragma unroll
  for (int ii = 0; ii < 2; ii++)
    if (nta[ii] >= 0)
      #pragma unroll
      for (int kt = 0; kt < 9; kt++)
        f0[ii][kt] = *(const bfrag8*)&M0f[((long)(nta[ii] * 9 + kt) * 64 + l) * 8];
  float bias0 = b0[ln];
  __syncthreads();
  for (int rb = 0; rb < 4; rb++){
    bfrag8 af[9];
    #pragma unroll
    for (int kt = 0; kt < 9; kt++)
      af[kt] = *(const bfrag8*)&xs[(rb * 16 + ln) * 296 + kt * 32 + q * 8];
    #pragma unroll
    for (int ii = 0; ii < 2; ii++){
      if (nta[ii] < 0) continue;
      ffrag4 acc = {bias0, bias0, bias0, bias0};
      #pragma unroll
      for (int kt = 0; kt < 9; kt++)
        acc = __builtin_amdgcn_mfma_f32_16x16x32_bf16(af[kt], f0[ii][kt], acc, 0, 0, 0);
      #pragma unroll
      for (int r = 0; r < 4; r++)
        h1e[(rb * 16 + q * 4 + r) * 200 + nta[ii] * 16 + ln] = f2b(elu_(acc[r]));
    }
  }
  int ntb[2] = {w, (w == 0) ? 8 : -1};
  bfrag8 f1[2][6];
  #pragma unroll
  for (int ii = 0; ii < 2; ii++)
    if (ntb[ii] >= 0)
      #pragma unroll
      for (int kt = 0; kt < 6; kt++)
        f1[ii][kt] = *(const bfrag8*)&M1f[((long)(ntb[ii] * 6 + kt) * 64 + l) * 8];
  __syncthreads();
  for (int rb = 0; rb < 4; rb++){
    bfrag8 af[6];
    #pragma unroll
    for (int kt = 0; kt < 6; kt++)
      af[kt] = *(const bfrag8*)&h1e[(rb * 16 + ln) * 200 + kt * 32 + q * 8];
    #pragma unroll
    for (int ii = 0; ii < 2; ii++){
      if (ntb[ii] < 0) continue;
      int n = ntb[ii] * 16 + ln;
      float bias = b1[n % 12];
      ffrag4 acc = {bias, bias, bias, bias};
      #pragma unroll
      for (int kt = 0; kt < 6; kt++)
        acc = __builtin_amdgcn_mfma_f32_16x16x32_bf16(af[kt], f1[ii][kt], acc, 0, 0, 0);
      #pragma unroll
      for (int r = 0; r < 4; r++)
        xs[(rb * 16 + q * 4 + r) * 144 + n] = f2b(elu_(acc[r]));
    }
  }
  __syncthreads();
  for (int i = t; i < 1152; i += 512)
    *(uint4*)&seq[row0 * 144 + (long)i * 8] = *(uint4*)&xs[i * 8];
}

// ---------------------------------------------------------------------------
// LSTM layer scan v3. 256 blocks x 512 threads (1 block/CU, 2 waves/SIMD).
// h-waves (0-3): one gate x 9 col-tiles each, Whh frags in regs; write fp32
// preacts to pad-20 Ph. x-waves (4-7): x-projection for step t+1 into
// parity-swapped Px (bias baked in), prefetch x(t+2). Gate math distributed
// over all 512 threads (4.5 cells each, c in regs). Y written coalesced
// after barrier 2 (store drain overlaps next step's MFMA).
// ---------------------------------------------------------------------------
template<bool HASX>
__global__ __launch_bounds__(512, 2) void k_scan(
    const ushort* __restrict__ Wf,    // [ntau*5][64][8] frags
    const ushort* __restrict__ seqin, // [24*4096][144] bf16 or null
    const float* __restrict__ bih, const float* __restrict__ bhh,
    const ushort* __restrict__ h0,    // [4096][144] bf16 or null
    ushort* __restrict__ Y,           // [98304][144] bf16 or null
    ushort* __restrict__ hT)          // [4096][144] bf16 or null
{
  __shared__ float Ph[11520];         // 576 gate-cols x 20 (16 rows + pad4)
  __shared__ float Px[2][11520];
  __shared__ ushort hl[2][2688];      // 16 rows x 168 (conflict-free)
  int t = threadIdx.x, rbk = blockIdx.x;
  int w = t >> 6, l = t & 63, q = l >> 4, ln = l & 15;
  if (t < 336){
    int row = t / 21, ch = t % 21;
    uint4 z = make_uint4(0u, 0u, 0u, 0u);
    *(uint4*)&hl[1][row * 168 + ch * 8] = z;
    if (h0 && ch < 18) z = *(const uint4*)&h0[((long)rbk * 16 + row) * 144 + ch * 8];
    *(uint4*)&hl[0][row * 168 + ch * 8] = z;
  }
  bool isH = (w < 4);
  bfrag8 wf[9][5];
  if (HASX || isH){
    #pragma unroll
    for (int i = 0; i < 9; i++){
      int tau = isH ? (w * 9 + i) : (36 + (w - 4) * 9 + i);
      #pragma unroll
      for (int kt = 0; kt < 5; kt++)
        wf[i][kt] = *(const bfrag8*)&Wf[((long)(tau * 5 + kt) * 64 + l) * 8];
    }
  }
  float cst[5] = {0.f, 0.f, 0.f, 0.f, 0.f};
  float biasx[9];
  bfrag8 axc[5];
  if (!isH){
    #pragma unroll
    for (int i = 0; i < 9; i++){
      int n = ((w - 4) * 9 + i) * 16 + ln;
      biasx[i] = bih[n] + bhh[n];
    }
    if (HASX){
      const ushort* xr = &seqin[((long)rbk * 16 + ln) * 144];
      #pragma unroll
      for (int kt = 0; kt < 5; kt++)
        axc[kt] = *(const bfrag8*)&xr[kt * 32 + q * 8];
      #pragma unroll
      for (int i = 0; i < 9; i++){
        ffrag4 acc = {biasx[i], biasx[i], biasx[i], biasx[i]};
        #pragma unroll
        for (int kt = 0; kt < 5; kt++)
          acc = __builtin_amdgcn_mfma_f32_16x16x32_bf16(axc[kt], wf[i][kt], acc, 0, 0, 0);
        *(ffrag4*)&Px[0][(((w - 4) * 9 + i) * 16 + ln) * 20 + q * 4] = acc;
      }
      const ushort* xr1 = &seqin[(4096L + (long)rbk * 16 + ln) * 144];
      #pragma unroll
      for (int kt = 0; kt < 5; kt++)
        axc[kt] = *(const bfrag8*)&xr1[kt * 32 + q * 8];
    } else {
      #pragma unroll
      for (int i = 0; i < 9; i++){
        ffrag4 acc = {biasx[i], biasx[i], biasx[i], biasx[i]};
        *(ffrag4*)&Px[0][(((w - 4) * 9 + i) * 16 + ln) * 20 + q * 4] = acc;
        *(ffrag4*)&Px[1][(((w - 4) * 9 + i) * 16 + ln) * 20 + q * 4] = acc;
      }
    }
  }
  __syncthreads();
  for (int ts = 0; ts < 24; ts++){
    int par = ts & 1;
    if (isH){
      bfrag8 ah[5];
      #pragma unroll
      for (int kt = 0; kt < 5; kt++)
        ah[kt] = *(const bfrag8*)&hl[par][ln * 168 + kt * 32 + q * 8];
      #pragma unroll
      for (int i = 0; i < 9; i++){
        ffrag4 acc = {0.f, 0.f, 0.f, 0.f};
        #pragma unroll
        for (int kt = 0; kt < 5; kt++)
          acc = __builtin_amdgcn_mfma_f32_16x16x32_bf16(ah[kt], wf[i][kt], acc, 0, 0, 0);
        *(ffrag4*)&Ph[((w * 9 + i) * 16 + ln) * 20 + q * 4] = acc;
      }
    } else if (HASX && ts < 23){
      #pragma unroll
      for (int i = 0; i < 9; i++){
        ffrag4 acc = {biasx[i], biasx[i], biasx[i], biasx[i]};
        #pragma unroll
        for (int kt = 0; kt < 5; kt++)
          acc = __builtin_amdgcn_mfma_f32_16x16x32_bf16(axc[kt], wf[i][kt], acc, 0, 0, 0);
        *(ffrag4*)&Px[par ^ 1][(((w - 4) * 9 + i) * 16 + ln) * 20 + q * 4] = acc;
      }
      if (ts < 22){
        const ushort* xr = &seqin[(((long)(ts + 2)) * 4096 + (long)rbk * 16 + ln) * 144];
        #pragma unroll
        for (int kt = 0; kt < 5; kt++)
          axc[kt] = *(const bfrag8*)&xr[kt * 32 + q * 8];
      }
    }
    __syncthreads();
    #pragma unroll
    for (int j = 0; j < 5; j++){
      int cell = j * 512 + t;
      if (cell < 2304){
        int col = cell >> 4, row = cell & 15;
        int a = col * 20 + row;
        float iv = Ph[a]        + Px[par][a];
        float fv = Ph[2880 + a] + Px[par][2880 + a];
        float gv = Ph[5760 + a] + Px[par][5760 + a];
        float ov = Ph[8640 + a] + Px[par][8640 + a];
        float cn = sigm(fv) * cst[j] + sigm(iv) * tanh_(gv);
        cst[j] = cn;
        hl[par ^ 1][row * 168 + col] = f2b(sigm(ov) * tanh_(cn));
      }
    }
    __syncthreads();
    if (Y && t < 288){
      int row = t / 18, ch = t % 18;
      *(uint4*)&Y[(((long)ts * 4096) + rbk * 16 + row) * 144 + ch * 8] =
          *(uint4*)&hl[par ^ 1][row * 168 + ch * 8];
    }
  }
  if (hT && t < 288){
    int row = t / 18, ch = t % 18;
    *(uint4*)&hT[((long)rbk * 16 + row) * 144 + ch * 8] = *(uint4*)&hl[0][row * 168 + ch * 8];
  }
}

// ---------------------------------------------------------------------------
// Tail: GAT3 -> GAT4 -> FC -> leaky -> fused MSE. 512 thr, 64 rows/block,
// grid 1536, ~64 KB LDS. Conflict-free strides (168, 200, 296).
// ---------------------------------------------------------------------------
__global__ __launch_bounds__(512) void k_tail(
    const ushort* __restrict__ Ya, const ushort* __restrict__ M3f, const float* __restrict__ b3,
    const ushort* __restrict__ M4f, const float* __restrict__ b4,
    const ushort* __restrict__ fWt, const float* __restrict__ fb,
    const float* __restrict__ x, float* __restrict__ out)
{
  __shared__ ushort h3e[64 * 200];    // 25600
  __shared__ ushort bufB[64 * 296];   // 37888: ys (stride 168) then h4e (stride 296)
  __shared__ float psum[64 * 8];
  ushort* ys = bufB;
  ushort* h4e = bufB;
  int t = threadIdx.x;
  long row0 = (long)blockIdx.x * 64;
  int w = t >> 6, l = t & 63, q = l >> 4, ln = l & 15;
  if (t < 192){
    int row = t / 3, seg = t % 3;
    *(uint4*)&ys[row * 168 + 144 + seg * 8] = make_uint4(0u, 0u, 0u, 0u);
  }
  for (int idx = t; idx < 1152; idx += 512){
    int row = idx / 18, ch = idx % 18;
    *(uint4*)&ys[row * 168 + ch * 8] = *(const uint4*)&Ya[(row0 + row) * 144 + (long)ch * 8];
  }
  int nta[2] = {w, (w < 4) ? 8 + w : -1};
  bfrag8 f3[2][5];
  #pragma unroll
  for (int ii = 0; ii < 2; ii++)
    if (nta[ii] >= 0)
      #pragma unroll
      for (int kt = 0; kt < 5; kt++)
        f3[ii][kt] = *(const bfrag8*)&M3f[((long)(nta[ii] * 5 + kt) * 64 + l) * 8];
  float bias3 = b3[ln];
  __syncthreads();
  for (int rb = 0; rb < 4; rb++){
    bfrag8 af[5];
    #pragma unroll
    for (int kt = 0; kt < 5; kt++)
      af[kt] = *(const bfrag8*)&ys[(rb * 16 + ln) * 168 + kt * 32 + q * 8];
    #pragma unroll
    for (int ii = 0; ii < 2; ii++){
      if (nta[ii] < 0) continue;
      ffrag4 acc = {bias3, bias3, bias3, bias3};
      #pragma unroll
      for (int kt = 0; kt < 5; kt++)
        acc = __builtin_amdgcn_mfma_f32_16x16x32_bf16(af[kt], f3[ii][kt], acc, 0, 0, 0);
      #pragma unroll
      for (int r = 0; r < 4; r++)
        h3e[(rb * 16 + q * 4 + r) * 200 + nta[ii] * 16 + ln] = f2b(elu_(acc[r]));
    }
  }
  int ntb[3] = {2 * w, 2 * w + 1, (w < 2) ? 16 + w : -1};
  bfrag8 f4[3][6];
  #pragma unroll
  for (int ii = 0; ii < 3; ii++)
    if (ntb[ii] >= 0)
      #pragma unroll
      for (int kt = 0; kt < 6; kt++)
        f4[ii][kt] = *(const bfrag8*)&M4f[((long)(ntb[ii] * 6 + kt) * 64 + l) * 8];
  __syncthreads();   // all ys reads done; bufB becomes h4e
  for (int rb = 0; rb < 4; rb++){
    bfrag8 af[6];
    #pragma unroll
    for (int kt = 0; kt < 6; kt++)
      af[kt] = *(const bfrag8*)&h3e[(rb * 16 + ln) * 200 + kt * 32 + q * 8];
    #pragma unroll
    for (int ii = 0; ii < 3; ii++){
      if (ntb[ii] < 0) continue;
      int n = ntb[ii] * 16 + ln;
      float bias = b4[n % 24];
      ffrag4 acc = {bias, bias, bias, bias};
      #pragma unroll
      for (int kt = 0; kt < 6; kt++)
        acc = __builtin_amdgcn_mfma_f32_16x16x32_bf16(af[kt], f4[ii][kt], acc, 0, 0, 0);
      #pragma unroll
      for (int r = 0; r < 4; r++)
        h4e[(rb * 16 + q * 4 + r) * 296 + n] = f2b(elu_(acc[r]));
    }
  }
  int ntc[3] = {2 * w, 2 * w + 1, (w == 0) ? 16 : -1};
  bfrag8 f5[3][9];
  float bias5[3] = {0.f, 0.f, 0.f};
  #pragma unroll
  for (int ii = 0; ii < 3; ii++)
    if (ntc[ii] >= 0){
      #pragma unroll
      for (int kt = 0; kt < 9; kt++)
        f5[ii][kt] = *(const bfrag8*)&fWt[((long)(ntc[ii] * 9 + kt) * 64 + l) * 8];
      int n = ntc[ii] * 16 + ln;
      bias5[ii] = (n < 264) ? fb[n] : 0.f;
    }
  __syncthreads();
  for (int rb = 0; rb < 4; rb++){
    bfrag8 af[9];
    #pragma unroll
    for (int kt = 0; kt < 9; kt++)
      af[kt] = *(const bfrag8*)&h4e[(rb * 16 + ln) * 296 + kt * 32 + q * 8];
    float s4[4] = {0.f, 0.f, 0.f, 0.f};
    #pragma unroll
    for (int ii = 0; ii < 3; ii++){
      if (ntc[ii] < 0) continue;
      ffrag4 acc = {bias5[ii], bias5[ii], bias5[ii], bias5[ii]};
      #pragma unroll
      for (int kt = 0; kt < 9; kt++)
        acc = __builtin_amdgcn_mfma_f32_16x16x32_bf16(af[kt], f5[ii][kt], acc, 0, 0, 0);
      int n = ntc[ii] * 16 + ln;
      if (n < 264){
        #pragma unroll
        for (int r = 0; r < 4; r++){
          float v = acc[r];
          v = v > 0.f ? v : 0.01f * v;
          long row = row0 + rb * 16 + q * 4 + r;
          float d = x[row * 264 + n] - v;
          s4[r] += d * d;
        }
      }
    }
    #pragma unroll
    for (int off = 1; off < 16; off <<= 1){
      #pragma unroll
      for (int r = 0; r < 4; r++) s4[r] += __shfl_xor(s4[r], off, 16);
    }
    if (ln == 0){
      #pragma unroll
      for (int r = 0; r < 4; r++) psum[(rb * 16 + q * 4 + r) * 8 + w] = s4[r];
    }
  }
  __syncthreads();
  if (t < 64){
    float s = 0.f;
    for (int k = 0; k < 8; k++) s += psum[t * 8 + k];
    out[row0 + t] = s * (1.0f / 264.0f);
  }
}

// ---------------------------------------------------------------------------
extern "C" void kernel_launch(void* const* d_in, const int* in_sizes, int n_in,
                              void* d_out, int out_size, void* d_ws, size_t ws_size,
                              hipStream_t stream)
{
  const float* x     = (const float*)d_in[0];
  const float* gW0   = (const float*)d_in[1];
  const float* gb0   = (const float*)d_in[2];
  const float* ga0   = (const float*)d_in[3];
  const float* gW1   = (const float*)d_in[4];
  const float* gb1   = (const float*)d_in[5];
  const float* ga1   = (const float*)d_in[6];
  const float* eWih0 = (const float*)d_in[7];
  const float* eWhh0 = (const float*)d_in[8];
  const float* ebih0 = (const float*)d_in[9];
  const float* ebhh0 = (const float*)d_in[10];
  const float* eWih1 = (const float*)d_in[11];
  const float* eWhh1 = (const float*)d_in[12];
  const float* ebih1 = (const float*)d_in[13];
  const float* ebhh1 = (const float*)d_in[14];
  const float* dWhh0 = (const float*)d_in[16];
  const float* dbih0 = (const float*)d_in[17];
  const float* dbhh0 = (const float*)d_in[18];
  const float* dWih1 = (const float*)d_in[19];
  const float* dWhh1 = (const float*)d_in[20];
  const float* dbih1 = (const float*)d_in[21];
  const float* dbhh1 = (const float*)d_in[22];
  const float* gW3   = (const float*)d_in[23];
  const float* gb3   = (const float*)d_in[24];
  const float* ga3   = (const float*)d_in[25];
  const float* gW4   = (const float*)d_in[26];
  const float* gb4   = (const float*)d_in[27];
  const float* ga4   = (const float*)d_in[28];
  const float* fW    = (const float*)d_in[29];
  const float* fb    = (const float*)d_in[30];

  char* ws = (char*)d_ws;
  ushort* M0f    = (ushort*)(ws + 9216);       // 110592 B
  ushort* M1f    = (ushort*)(ws + 119808);     // 55296 B
  ushort* M3f    = (ushort*)(ws + 175104);     // 61440 B
  ushort* M4f    = (ushort*)(ws + 236544);     // 110592 B
  ushort* fWt    = (ushort*)(ws + 347136);     // 156672 B
  ushort* lstmF  = (ushort*)(ws + 503808);     // 1290240 B
  ushort* seq    = (ushort*)(ws + 1794048);    // 28311552 B
  ushort* Ya     = (ushort*)(ws + 30105600);   // 28311552 B
  ushort* Yb     = (ushort*)(ws + 58417152);   // 28311552 B
  ushort* hT0    = (ushort*)(ws + 86728704);   // 1179648 B
  ushort* hT1    = (ushort*)(ws + 87908352);   // 1179648 B
  float* out = (float*)d_out;

  k_prep_all<<<dim3(360, 5), 64, 0, stream>>>(eWih0, eWhh0, eWih1, eWhh1,
                                              dWhh0, dWih1, dWhh1, fW, lstmF, fWt);
  k_probs<<<1, 576, 0, stream>>>(x, nullptr, 22,
                                 gW0, gb0, ga0, 16, 4,
                                 gW1, gb1, ga1, 12, 3,
                                 M0f, 9, M1f, 6);
  k_gat01<<<1536, 512, 0, stream>>>(x, M0f, gb0, M1f, gb1, seq);

  // encoder L0
  k_scan<true><<<256, 512, 0, stream>>>(lstmF + 0L,      seq, ebih0, ebhh0, nullptr, Ya, hT0);
  // encoder L1 (only final h needed)
  k_scan<true><<<256, 512, 0, stream>>>(lstmF + 184320L, Ya, ebih1, ebhh1, nullptr, nullptr, hT1);
  // decoder L0 (zero input)
  k_scan<false><<<256, 512, 0, stream>>>(lstmF + 368640L, nullptr, dbih0, dbhh0, hT0, Yb, nullptr);
  // decoder L1
  k_scan<true><<<256, 512, 0, stream>>>(lstmF + 460800L, Yb, dbih1, dbhh1, hT1, Ya, nullptr);

  k_probs<<<1, 576, 0, stream>>>(nullptr, Ya, 12,
                                 gW3, gb3, ga3, 16, 4,
                                 gW4, gb4, ga4, 24, 6,
                                 M3f, 5, M4f, 6);
  k_tail<<<1536, 512, 0, stream>>>(Ya, M3f, gb3, M4f, gb4, fWt, fb, x, out);
}

// Round 6
// 658.668 us; speedup vs baseline: 1.3041x; 1.3041x over previous
//
#include <hip/hip_runtime.h>

#define DI __device__ __forceinline__

typedef short bfrag8 __attribute__((ext_vector_type(8)));
typedef float ffrag4 __attribute__((ext_vector_type(4)));

DI ushort f2b(float f){
  union { float f; unsigned u; } v; v.f = f;
  unsigned u = v.u;
  u += 0x7FFF + ((u >> 16) & 1);   // round-to-nearest-even
  return (ushort)(u >> 16);
}
DI float b2f(ushort h){
  union { unsigned u; float f; } v; v.u = ((unsigned)h) << 16;
  return v.f;
}
DI float sigm(float x){ return 1.0f / (1.0f + __expf(-x)); }
DI float tanh_(float x){ return 1.0f - 2.0f / (1.0f + __expf(2.0f * x)); }
DI float elu_(float x){ return x > 0.f ? x : __expf(x) - 1.f; }

// ---------------------------------------------------------------------------
// Attention probs for a pair of GAT layers from sample 0 AND build the fused
// linear-operator MFMA B-frags for both layers. 1 block x 576 threads.
// ---------------------------------------------------------------------------
__global__ void k_probs(const float* xf, const ushort* xb, int in_c,
                        const float* W1, const float* b1, const float* a1, int hc1, int c1,
                        const float* W2, const float* b2, const float* a2, int hc2, int c2,
                        ushort* __restrict__ M1dst, int KT1,
                        ushort* __restrict__ M2dst, int KT2)
{
  __shared__ float xs[12 * 22];
  __shared__ float h1[12 * 16];
  __shared__ float lg[576];
  __shared__ float prA[576];
  __shared__ float prB[576];
  __shared__ float h1e[12 * 16];
  __shared__ float h2[12 * 24];
  const int t = threadIdx.x;
  const unsigned adj[12] = {0xC21u,0x482u,0x844u,0x048u,0x030u,0x031u,
                            0x44Cu,0x282u,0xF00u,0x780u,0xF43u,0xD05u};
  if (t < 12 * in_c){
    if (xf) xs[t] = xf[t];
    else    xs[t] = b2f(xb[t]);
  }
  __syncthreads();
  if (t < 12 * hc1){
    int i = t / hc1, o = t % hc1;
    float v = b1[o];
    for (int k = 0; k < in_c; k++) v += xs[i * in_c + k] * W1[k * hc1 + o];
    h1[t] = v;
  }
  __syncthreads();
  {
    int h = t / 144, ij = t % 144, i = ij / 12, j = ij % 12;
    float v;
    if ((adj[i] >> j) & 1){
      v = 0.f;
      for (int c = 0; c < c1; c++)
        v += a1[h*2*c1 + c] * h1[i*hc1 + h*c1 + c] + a1[h*2*c1 + c1 + c] * h1[j*hc1 + h*c1 + c];
      v = v > 0.f ? v : 0.2f * v;
    } else v = -9e15f;
    lg[t] = v;
  }
  __syncthreads();
  if (t < 48){
    int h = t / 12, i = t % 12;
    const float* row = &lg[h*144 + i*12];
    float m = row[0];
    for (int j = 1; j < 12; j++) m = fmaxf(m, row[j]);
    float e[12], s = 0.f;
    for (int j = 0; j < 12; j++){ e[j] = __expf(row[j] - m); s += e[j]; }
    float inv = 1.f / s;
    for (int j = 0; j < 12; j++) prA[h*144 + i*12 + j] = e[j] * inv;
  }
  __syncthreads();
  if (t < 12 * hc1){
    int i = t / hc1, o = t % hc1, h = o / c1;
    float v = 0.f;
    for (int j = 0; j < 12; j++) v += prA[h*144 + i*12 + j] * h1[j*hc1 + o];
    h1e[t] = elu_(v);
  }
  __syncthreads();
  if (t < 12 * hc2){
    int i = t / hc2, o = t % hc2;
    float v = b2[o];
    for (int k = 0; k < hc1; k++) v += h1e[i*hc1 + k] * W2[k*hc2 + o];
    h2[t] = v;
  }
  __syncthreads();
  {
    int h = t / 144, ij = t % 144, i = ij / 12, j = ij % 12;
    float v;
    if ((adj[i] >> j) & 1){
      v = 0.f;
      for (int c = 0; c < c2; c++)
        v += a2[h*2*c2 + c] * h2[i*hc2 + h*c2 + c] + a2[h*2*c2 + c2 + c] * h2[j*hc2 + h*c2 + c];
      v = v > 0.f ? v : 0.2f * v;
    } else v = -9e15f;
    lg[t] = v;
  }
  __syncthreads();
  if (t < 48){
    int h = t / 12, i = t % 12;
    const float* row = &lg[h*144 + i*12];
    float m = row[0];
    for (int j = 1; j < 12; j++) m = fmaxf(m, row[j]);
    float e[12], s = 0.f;
    for (int j = 0; j < 12; j++){ e[j] = __expf(row[j] - m); s += e[j]; }
    float inv = 1.f / s;
    for (int j = 0; j < 12; j++) prB[h*144 + i*12 + j] = e[j] * inv;
  }
  __syncthreads();
  {
    int NT = (12 * hc1) / 16, K = 12 * in_c;
    for (int idx = t; idx < NT * KT1 * 64; idx += 576){
      int bI = idx >> 6, li = idx & 63;
      int kt = bI % KT1, nt = bI / KT1;
      int n = nt * 16 + (li & 15);
      int i = n / hc1, o = n % hc1;
      union { ushort u[8]; uint4 v; } pk;
      #pragma unroll
      for (int j = 0; j < 8; j++){
        int k = kt * 32 + (li >> 4) * 8 + j;
        float v = 0.f;
        if (k < K){
          int jj = k / in_c, kk = k % in_c;
          v = prA[(o / c1) * 144 + i * 12 + jj] * W1[kk * hc1 + o];
        }
        pk.u[j] = f2b(v);
      }
      *(uint4*)&M1dst[(long)idx * 8] = pk.v;
    }
  }
  {
    int NT = (12 * hc2) / 16, K = 12 * hc1;
    for (int idx = t; idx < NT * KT2 * 64; idx += 576){
      int bI = idx >> 6, li = idx & 63;
      int kt = bI % KT2, nt = bI / KT2;
      int n = nt * 16 + (li & 15);
      int i = n / hc2, o = n % hc2;
      union { ushort u[8]; uint4 v; } pk;
      #pragma unroll
      for (int j = 0; j < 8; j++){
        int k = kt * 32 + (li >> 4) * 8 + j;
        float v = 0.f;
        if (k < K){
          int jj = k / hc1, kk = k % hc1;
          v = prB[(o / c2) * 144 + i * 12 + jj] * W2[kk * hc2 + o];
        }
        pk.u[j] = f2b(v);
      }
      *(uint4*)&M2dst[(long)idx * 8] = pk.v;
    }
  }
}

// ---------------------------------------------------------------------------
// Prep LSTM weights (y=0..3) and fW (y=4) into frag layouts. grid (360,5)x64.
// ---------------------------------------------------------------------------
__global__ void k_prep_all(const float* eWih0, const float* eWhh0,
                           const float* eWih1, const float* eWhh1,
                           const float* dWhh0,
                           const float* dWih1, const float* dWhh1,
                           const float* fW,
                           ushort* __restrict__ lstmF, ushort* __restrict__ fWt)
{
  int y = blockIdx.y;
  int l = threadIdx.x, ln = l & 15, q = l >> 4;
  if (y == 4){
    int bI = blockIdx.x;
    if (bI >= 153) return;
    int nt = bI / 9, kt = bI % 9;
    int n = nt * 16 + ln;
    union { ushort u[8]; uint4 v; } pk;
    #pragma unroll
    for (int j = 0; j < 8; j++){
      int k = kt * 32 + q * 8 + j;
      float v = (k < 288 && n < 264) ? fW[k * 264 + n] : 0.f;
      pk.u[j] = f2b(v);
    }
    *(uint4*)&fWt[((long)(bI * 64 + l)) * 8] = pk.v;
    return;
  }
  const float* Wh; const float* Wx; long off; int ntau;
  if (y == 0){ Wh = eWhh0; Wx = eWih0; off = 0;      ntau = 72; }
  else if (y == 1){ Wh = eWhh1; Wx = eWih1; off = 184320; ntau = 72; }
  else if (y == 2){ Wh = dWhh0; Wx = dWhh0; off = 368640; ntau = 36; }
  else { Wh = dWhh1; Wx = dWih1; off = 460800; ntau = 72; }
  int bI = blockIdx.x;                 // tau*5 + kt
  int tau = bI / 5, kt = bI % 5;
  if (tau >= ntau) return;
  const float* W = (tau < 36) ? Wh : Wx;
  int tt = (tau < 36) ? tau : tau - 36;
  int gt = tt / 9, ct = tt % 9;
  int n = gt * 144 + ct * 16 + ln;
  ushort* d = lstmF + off;
  union { ushort u[8]; uint4 v; } pk;
  #pragma unroll
  for (int j = 0; j < 8; j++){
    int k = kt * 32 + q * 8 + j;
    float v = (k < 144) ? W[(long)n * 144 + k] : 0.f;
    pk.u[j] = f2b(v);
  }
  *(uint4*)&d[((long)(bI * 64 + l)) * 8] = pk.v;
}

// ---------------------------------------------------------------------------
// GAT layers 0+1 as fused-operator MFMA GEMMs. 512 thr, 64 rows/block.
// ---------------------------------------------------------------------------
__global__ __launch_bounds__(512) void k_gat01(
    const float* __restrict__ x, const ushort* __restrict__ M0f, const float* __restrict__ b0,
    const ushort* __restrict__ M1f, const float* __restrict__ b1,
    ushort* __restrict__ seq)
{
  __shared__ ushort xs[64 * 296];
  __shared__ ushort h1e[64 * 200];
  int t = threadIdx.x;
  long row0 = (long)blockIdx.x * 64;
  int w = t >> 6, l = t & 63, q = l >> 4, ln = l & 15;
  if (t < 256){
    int row = t >> 2, seg = t & 3;
    *(uint4*)&xs[row * 296 + 264 + seg * 8] = make_uint4(0u, 0u, 0u, 0u);
  }
  for (int idx = t; idx < 4224; idx += 512){
    int row = idx / 66, c4 = idx % 66;
    float4 v = *(const float4*)&x[(row0 + row) * 264 + c4 * 4];
    ushort4 o; o.x = f2b(v.x); o.y = f2b(v.y); o.z = f2b(v.z); o.w = f2b(v.w);
    *(ushort4*)&xs[row * 296 + c4 * 4] = o;
  }
  int nta[2] = {w, (w < 4) ? 8 + w : -1};
  bfrag8 f0[2][9];
  #pragma unroll
  for (int ii = 0; ii < 2; ii++)
    if (nta[ii] >= 0)
      #pragma unroll
      for (int kt = 0; kt < 9; kt++)
        f0[ii][kt] = *(const bfrag8*)&M0f[((long)(nta[ii] * 9 + kt) * 64 + l) * 8];
  float bias0 = b0[ln];
  __syncthreads();
  for (int rb = 0; rb < 4; rb++){
    bfrag8 af[9];
    #pragma unroll
    for (int kt = 0; kt < 9; kt++)
      af[kt] = *(const bfrag8*)&xs[(rb * 16 + ln) * 296 + kt * 32 + q * 8];
    #pragma unroll
    for (int ii = 0; ii < 2; ii++){
      if (nta[ii] < 0) continue;
      ffrag4 acc = {bias0, bias0, bias0, bias0};
      #pragma unroll
      for (int kt = 0; kt < 9; kt++)
        acc = __builtin_amdgcn_mfma_f32_16x16x32_bf16(af[kt], f0[ii][kt], acc, 0, 0, 0);
      #pragma unroll
      for (int r = 0; r < 4; r++)
        h1e[(rb * 16 + q * 4 + r) * 200 + nta[ii] * 16 + ln] = f2b(elu_(acc[r]));
    }
  }
  int ntb[2] = {w, (w == 0) ? 8 : -1};
  bfrag8 f1[2][6];
  #pragma unroll
  for (int ii = 0; ii < 2; ii++)
    if (ntb[ii] >= 0)
      #pragma unroll
      for (int kt = 0; kt < 6; kt++)
        f1[ii][kt] = *(const bfrag8*)&M1f[((long)(ntb[ii] * 6 + kt) * 64 + l) * 8];
  __syncthreads();
  for (int rb = 0; rb < 4; rb++){
    bfrag8 af[6];
    #pragma unroll
    for (int kt = 0; kt < 6; kt++)
      af[kt] = *(const bfrag8*)&h1e[(rb * 16 + ln) * 200 + kt * 32 + q * 8];
    #pragma unroll
    for (int ii = 0; ii < 2; ii++){
      if (ntb[ii] < 0) continue;
      int n = ntb[ii] * 16 + ln;
      float bias = b1[n % 12];
      ffrag4 acc = {bias, bias, bias, bias};
      #pragma unroll
      for (int kt = 0; kt < 6; kt++)
        acc = __builtin_amdgcn_mfma_f32_16x16x32_bf16(af[kt], f1[ii][kt], acc, 0, 0, 0);
      #pragma unroll
      for (int r = 0; r < 4; r++)
        xs[(rb * 16 + q * 4 + r) * 144 + n] = f2b(elu_(acc[r]));
    }
  }
  __syncthreads();
  for (int i = t; i < 1152; i += 512)
    *(uint4*)&seq[row0 * 144 + (long)i * 8] = *(uint4*)&xs[i * 8];
}

// ---------------------------------------------------------------------------
// LSTM layer scan v4 (v2 revert + fixes). 256 blocks x 512 threads.
// h-waves (0-3): col-tiles {2w,2w+1} x ALL 4 gates in registers -> in-lane
// gate math, no LDS roundtrip; + gate w of tile 8 via small P8.
// x-waves (4-7): x-projection for step t+1 into parity-swapped pad-20 Px
// (bias baked in), prefetch x(t+2); Y written coalesced by x-waves after
// barrier 2 (h-waves issue no global stores on the serial chain).
// ---------------------------------------------------------------------------
template<bool HASX>
__global__ __launch_bounds__(512, 2) void k_scan(
    const ushort* __restrict__ Wf,    // [ntau*5][64][8] frags
    const ushort* __restrict__ seqin, // [24*4096][144] bf16 or null
    const float* __restrict__ bih, const float* __restrict__ bhh,
    const ushort* __restrict__ h0,    // [4096][144] bf16 or null
    ushort* __restrict__ Y,           // [98304][144] bf16 or null
    ushort* __restrict__ hT)          // [4096][144] bf16 or null
{
  __shared__ float Px[2][11520];      // [gate*144+col]*20 + row (pad 20)
  __shared__ float P8[1280];          // tile-8 preacts [gate*16+col]*20 + row
  __shared__ ushort hl[2][2688];      // 16 rows x 168
  int t = threadIdx.x, rbk = blockIdx.x;
  int w = t >> 6, l = t & 63, q = l >> 4, ln = l & 15;
  if (t < 336){
    int row = t / 21, ch = t % 21;
    uint4 z = make_uint4(0u, 0u, 0u, 0u);
    *(uint4*)&hl[1][row * 168 + ch * 8] = z;
    if (h0 && ch < 18) z = *(const uint4*)&h0[((long)rbk * 16 + row) * 144 + ch * 8];
    *(uint4*)&hl[0][row * 168 + ch * 8] = z;
  }
  if (w < 4){
    // ------------------------- h-waves -------------------------
    bfrag8 wh[2][4][5], w8[5];
    #pragma unroll
    for (int ci = 0; ci < 2; ci++)
      #pragma unroll
      for (int gt = 0; gt < 4; gt++)
        #pragma unroll
        for (int kt = 0; kt < 5; kt++)
          wh[ci][gt][kt] = *(const bfrag8*)&Wf[((long)((gt * 9 + 2 * w + ci) * 5 + kt) * 64 + l) * 8];
    #pragma unroll
    for (int kt = 0; kt < 5; kt++)
      w8[kt] = *(const bfrag8*)&Wf[((long)((w * 9 + 8) * 5 + kt) * 64 + l) * 8];
    float cst[2][4] = {};
    float c8 = 0.f;
    __syncthreads();
    for (int ts = 0; ts < 24; ts++){
      int par = ts & 1;
      const ushort* hlr = &hl[par][0];
      ushort* hlw = &hl[par ^ 1][0];
      bfrag8 ah[5];
      #pragma unroll
      for (int kt = 0; kt < 5; kt++)
        ah[kt] = *(const bfrag8*)&hlr[ln * 168 + kt * 32 + q * 8];
      #pragma unroll
      for (int ci = 0; ci < 2; ci++){
        int ct = 2 * w + ci;
        ffrag4 acc[4];
        #pragma unroll
        for (int gt = 0; gt < 4; gt++)
          acc[gt] = *(ffrag4*)&Px[par][(gt * 144 + ct * 16 + ln) * 20 + q * 4];
        #pragma unroll
        for (int gt = 0; gt < 4; gt++)
          #pragma unroll
          for (int kt = 0; kt < 5; kt++)
            acc[gt] = __builtin_amdgcn_mfma_f32_16x16x32_bf16(ah[kt], wh[ci][gt][kt], acc[gt], 0, 0, 0);
        #pragma unroll
        for (int r = 0; r < 4; r++){
          float cn = sigm(acc[1][r]) * cst[ci][r] + sigm(acc[0][r]) * tanh_(acc[2][r]);
          cst[ci][r] = cn;
          hlw[(q * 4 + r) * 168 + ct * 16 + ln] = f2b(sigm(acc[3][r]) * tanh_(cn));
        }
      }
      {
        ffrag4 a8 = *(ffrag4*)&Px[par][(w * 144 + 128 + ln) * 20 + q * 4];
        #pragma unroll
        for (int kt = 0; kt < 5; kt++)
          a8 = __builtin_amdgcn_mfma_f32_16x16x32_bf16(ah[kt], w8[kt], a8, 0, 0, 0);
        *(ffrag4*)&P8[(w * 16 + ln) * 20 + q * 4] = a8;
      }
      __syncthreads();   // barrier 1: P8 visible among h-waves
      if (t < 256){
        int row = t >> 4, c8c = t & 15;
        float iv = P8[(0 * 16 + c8c) * 20 + row];
        float fv = P8[(1 * 16 + c8c) * 20 + row];
        float gv = P8[(2 * 16 + c8c) * 20 + row];
        float ov = P8[(3 * 16 + c8c) * 20 + row];
        float cn = sigm(fv) * c8 + sigm(iv) * tanh_(gv);
        c8 = cn;
        hl[par ^ 1][row * 168 + 128 + c8c] = f2b(sigm(ov) * tanh_(cn));
      }
      __syncthreads();   // barrier 2: hl[par^1] complete
    }
  } else {
    // ------------------------- x-waves -------------------------
    int j = w - 4;
    bfrag8 wx[9][5];
    float biasx[9];
    bfrag8 axc[5];
    #pragma unroll
    for (int i = 0; i < 9; i++){
      int n = (j * 9 + i) * 16 + ln;
      biasx[i] = bih[n] + bhh[n];
      if (HASX)
        #pragma unroll
        for (int kt = 0; kt < 5; kt++)
          wx[i][kt] = *(const bfrag8*)&Wf[((long)((36 + j * 9 + i) * 5 + kt) * 64 + l) * 8];
    }
    if (HASX){
      const ushort* xr = &seqin[((long)rbk * 16 + ln) * 144];
      #pragma unroll
      for (int kt = 0; kt < 5; kt++)
        axc[kt] = *(const bfrag8*)&xr[kt * 32 + q * 8];
      #pragma unroll
      for (int i = 0; i < 9; i++){
        ffrag4 acc = {biasx[i], biasx[i], biasx[i], biasx[i]};
        #pragma unroll
        for (int kt = 0; kt < 5; kt++)
          acc = __builtin_amdgcn_mfma_f32_16x16x32_bf16(axc[kt], wx[i][kt], acc, 0, 0, 0);
        *(ffrag4*)&Px[0][((j * 9 + i) * 16 + ln) * 20 + q * 4] = acc;
      }
      const ushort* xr1 = &seqin[(4096L + (long)rbk * 16 + ln) * 144];
      #pragma unroll
      for (int kt = 0; kt < 5; kt++)
        axc[kt] = *(const bfrag8*)&xr1[kt * 32 + q * 8];
    } else {
      #pragma unroll
      for (int i = 0; i < 9; i++){
        ffrag4 acc = {biasx[i], biasx[i], biasx[i], biasx[i]};
        *(ffrag4*)&Px[0][((j * 9 + i) * 16 + ln) * 20 + q * 4] = acc;
        *(ffrag4*)&Px[1][((j * 9 + i) * 16 + ln) * 20 + q * 4] = acc;
      }
    }
    __syncthreads();
    for (int ts = 0; ts < 24; ts++){
      int par = ts & 1;
      if (HASX && ts < 23){
        #pragma unroll
        for (int i = 0; i < 9; i++){
          ffrag4 acc = {biasx[i], biasx[i], biasx[i], biasx[i]};
          #pragma unroll
          for (int kt = 0; kt < 5; kt++)
            acc = __builtin_amdgcn_mfma_f32_16x16x32_bf16(axc[kt], wx[i][kt], acc, 0, 0, 0);
          *(ffrag4*)&Px[par ^ 1][((j * 9 + i) * 16 + ln) * 20 + q * 4] = acc;
        }
        if (ts < 22){
          const ushort* xr = &seqin[(((long)(ts + 2)) * 4096 + (long)rbk * 16 + ln) * 144];
          #pragma unroll
          for (int kt = 0; kt < 5; kt++)
            axc[kt] = *(const bfrag8*)&xr[kt * 32 + q * 8];
        }
      }
      __syncthreads();   // barrier 1
      __syncthreads();   // barrier 2: hl[par^1] complete
      if (Y){
        int idx = t - 256;
        int row = idx / 18, ch = idx % 18;
        *(uint4*)&Y[(((long)ts * 4096) + rbk * 16 + row) * 144 + ch * 8] =
            *(uint4*)&hl[par ^ 1][row * 168 + ch * 8];
        if (idx < 32){
          int row2 = (idx + 256) / 18, ch2 = (idx + 256) % 18;
          *(uint4*)&Y[(((long)ts * 4096) + rbk * 16 + row2) * 144 + ch2 * 8] =
              *(uint4*)&hl[par ^ 1][row2 * 168 + ch2 * 8];
        }
      }
    }
  }
  if (hT && t < 288){
    int row = t / 18, ch = t % 18;
    *(uint4*)&hT[((long)rbk * 16 + row) * 144 + ch * 8] = *(uint4*)&hl[0][row * 168 + ch * 8];
  }
}

// ---------------------------------------------------------------------------
// Tail: GAT3 -> GAT4 -> FC -> leaky -> fused MSE. 512 thr, 64 rows/block.
// ---------------------------------------------------------------------------
__global__ __launch_bounds__(512) void k_tail(
    const ushort* __restrict__ Ya, const ushort* __restrict__ M3f, const float* __restrict__ b3,
    const ushort* __restrict__ M4f, const float* __restrict__ b4,
    const ushort* __restrict__ fWt, const float* __restrict__ fb,
    const float* __restrict__ x, float* __restrict__ out)
{
  __shared__ ushort h3e[64 * 200];
  __shared__ ushort bufB[64 * 296];
  __shared__ float psum[64 * 8];
  ushort* ys = bufB;
  ushort* h4e = bufB;
  int t = threadIdx.x;
  long row0 = (long)blockIdx.x * 64;
  int w = t >> 6, l = t & 63, q = l >> 4, ln = l & 15;
  if (t < 192){
    int row = t / 3, seg = t % 3;
    *(uint4*)&ys[row * 168 + 144 + seg * 8] = make_uint4(0u, 0u, 0u, 0u);
  }
  for (int idx = t; idx < 1152; idx += 512){
    int row = idx / 18, ch = idx % 18;
    *(uint4*)&ys[row * 168 + ch * 8] = *(const uint4*)&Ya[(row0 + row) * 144 + (long)ch * 8];
  }
  int nta[2] = {w, (w < 4) ? 8 + w : -1};
  bfrag8 f3[2][5];
  #pragma unroll
  for (int ii = 0; ii < 2; ii++)
    if (nta[ii] >= 0)
      #pragma unroll
      for (int kt = 0; kt < 5; kt++)
        f3[ii][kt] = *(const bfrag8*)&M3f[((long)(nta[ii] * 5 + kt) * 64 + l) * 8];
  float bias3 = b3[ln];
  __syncthreads();
  for (int rb = 0; rb < 4; rb++){
    bfrag8 af[5];
    #pragma unroll
    for (int kt = 0; kt < 5; kt++)
      af[kt] = *(const bfrag8*)&ys[(rb * 16 + ln) * 168 + kt * 32 + q * 8];
    #pragma unroll
    for (int ii = 0; ii < 2; ii++){
      if (nta[ii] < 0) continue;
      ffrag4 acc = {bias3, bias3, bias3, bias3};
      #pragma unroll
      for (int kt = 0; kt < 5; kt++)
        acc = __builtin_amdgcn_mfma_f32_16x16x32_bf16(af[kt], f3[ii][kt], acc, 0, 0, 0);
      #pragma unroll
      for (int r = 0; r < 4; r++)
        h3e[(rb * 16 + q * 4 + r) * 200 + nta[ii] * 16 + ln] = f2b(elu_(acc[r]));
    }
  }
  int ntb[3] = {2 * w, 2 * w + 1, (w < 2) ? 16 + w : -1};
  bfrag8 f4[3][6];
  #pragma unroll
  for (int ii = 0; ii < 3; ii++)
    if (ntb[ii] >= 0)
      #pragma unroll
      for (int kt = 0; kt < 6; kt++)
        f4[ii][kt] = *(const bfrag8*)&M4f[((long)(ntb[ii] * 6 + kt) * 64 + l) * 8];
  __syncthreads();
  for (int rb = 0; rb < 4; rb++){
    bfrag8 af[6];
    #pragma unroll
    for (int kt = 0; kt < 6; kt++)
      af[kt] = *(const bfrag8*)&h3e[(rb * 16 + ln) * 200 + kt * 32 + q * 8];
    #pragma unroll
    for (int ii = 0; ii < 3; ii++){
      if (ntb[ii] < 0) continue;
      int n = ntb[ii] * 16 + ln;
      float bias = b4[n % 24];
      ffrag4 acc = {bias, bias, bias, bias};
      #pragma unroll
      for (int kt = 0; kt < 6; kt++)
        acc = __builtin_amdgcn_mfma_f32_16x16x32_bf16(af[kt], f4[ii][kt], acc, 0, 0, 0);
      #pragma unroll
      for (int r = 0; r < 4; r++)
        h4e[(rb * 16 + q * 4 + r) * 296 + n] = f2b(elu_(acc[r]));
    }
  }
  int ntc[3] = {2 * w, 2 * w + 1, (w == 0) ? 16 : -1};
  bfrag8 f5[3][9];
  float bias5[3] = {0.f, 0.f, 0.f};
  #pragma unroll
  for (int ii = 0; ii < 3; ii++)
    if (ntc[ii] >= 0){
      #pragma unroll
      for (int kt = 0; kt < 9; kt++)
        f5[ii][kt] = *(const bfrag8*)&fWt[((long)(ntc[ii] * 9 + kt) * 64 + l) * 8];
      int n = ntc[ii] * 16 + ln;
      bias5[ii] = (n < 264) ? fb[n] : 0.f;
    }
  __syncthreads();
  for (int rb = 0; rb < 4; rb++){
    bfrag8 af[9];
    #pragma unroll
    for (int kt = 0; kt < 9; kt++)
      af[kt] = *(const bfrag8*)&h4e[(rb * 16 + ln) * 296 + kt * 32 + q * 8];
    float s4[4] = {0.f, 0.f, 0.f, 0.f};
    #pragma unroll
    for (int ii = 0; ii < 3; ii++){
      if (ntc[ii] < 0) continue;
      ffrag4 acc = {bias5[ii], bias5[ii], bias5[ii], bias5[ii]};
      #pragma unroll
      for (int kt = 0; kt < 9; kt++)
        acc = __builtin_amdgcn_mfma_f32_16x16x32_bf16(af[kt], f5[ii][kt], acc, 0, 0, 0);
      int n = ntc[ii] * 16 + ln;
      if (n < 264){
        #pragma unroll
        for (int r = 0; r < 4; r++){
          float v = acc[r];
          v = v > 0.f ? v : 0.01f * v;
          long row = row0 + rb * 16 + q * 4 + r;
          float d = x[row * 264 + n] - v;
          s4[r] += d * d;
        }
      }
    }
    #pragma unroll
    for (int off = 1; off < 16; off <<= 1){
      #pragma unroll
      for (int r = 0; r < 4; r++) s4[r] += __shfl_xor(s4[r], off, 16);
    }
    if (ln == 0){
      #pragma unroll
      for (int r = 0; r < 4; r++) psum[(rb * 16 + q * 4 + r) * 8 + w] = s4[r];
    }
  }
  __syncthreads();
  if (t < 64){
    float s = 0.f;
    for (int k = 0; k < 8; k++) s += psum[t * 8 + k];
    out[row0 + t] = s * (1.0f / 264.0f);
  }
}

// ---------------------------------------------------------------------------
extern "C" void kernel_launch(void* const* d_in, const int* in_sizes, int n_in,
                              void* d_out, int out_size, void* d_ws, size_t ws_size,
                              hipStream_t stream)
{
  const float* x     = (const float*)d_in[0];
  const float* gW0   = (const float*)d_in[1];
  const float* gb0   = (const float*)d_in[2];
  const float* ga0   = (const float*)d_in[3];
  const float* gW1   = (const float*)d_in[4];
  const float* gb1   = (const float*)d_in[5];
  const float* ga1   = (const float*)d_in[6];
  const float* eWih0 = (const float*)d_in[7];
  const float* eWhh0 = (const float*)d_in[8];
  const float* ebih0 = (const float*)d_in[9];
  const float* ebhh0 = (const float*)d_in[10];
  const float* eWih1 = (const float*)d_in[11];
  const float* eWhh1 = (const float*)d_in[12];
  const float* ebih1 = (const float*)d_in[13];
  const float* ebhh1 = (const float*)d_in[14];
  const float* dWhh0 = (const float*)d_in[16];
  const float* dbih0 = (const float*)d_in[17];
  const float* dbhh0 = (const float*)d_in[18];
  const float* dWih1 = (const float*)d_in[19];
  const float* dWhh1 = (const float*)d_in[20];
  const float* dbih1 = (const float*)d_in[21];
  const float* dbhh1 = (const float*)d_in[22];
  const float* gW3   = (const float*)d_in[23];
  const float* gb3   = (const float*)d_in[24];
  const float* ga3   = (const float*)d_in[25];
  const float* gW4   = (const float*)d_in[26];
  const float* gb4   = (const float*)d_in[27];
  const float* ga4   = (const float*)d_in[28];
  const float* fW    = (const float*)d_in[29];
  const float* fb    = (const float*)d_in[30];

  char* ws = (char*)d_ws;
  ushort* M0f    = (ushort*)(ws + 9216);       // 110592 B
  ushort* M1f    = (ushort*)(ws + 119808);     // 55296 B
  ushort* M3f    = (ushort*)(ws + 175104);     // 61440 B
  ushort* M4f    = (ushort*)(ws + 236544);     // 110592 B
  ushort* fWt    = (ushort*)(ws + 347136);     // 156672 B
  ushort* lstmF  = (ushort*)(ws + 503808);     // 1290240 B
  ushort* seq    = (ushort*)(ws + 1794048);    // 28311552 B
  ushort* Ya     = (ushort*)(ws + 30105600);   // 28311552 B
  ushort* Yb     = (ushort*)(ws + 58417152);   // 28311552 B
  ushort* hT0    = (ushort*)(ws + 86728704);   // 1179648 B
  ushort* hT1    = (ushort*)(ws + 87908352);   // 1179648 B
  float* out = (float*)d_out;

  k_prep_all<<<dim3(360, 5), 64, 0, stream>>>(eWih0, eWhh0, eWih1, eWhh1,
                                              dWhh0, dWih1, dWhh1, fW, lstmF, fWt);
  k_probs<<<1, 576, 0, stream>>>(x, nullptr, 22,
                                 gW0, gb0, ga0, 16, 4,
                                 gW1, gb1, ga1, 12, 3,
                                 M0f, 9, M1f, 6);
  k_gat01<<<1536, 512, 0, stream>>>(x, M0f, gb0, M1f, gb1, seq);

  // encoder L0
  k_scan<true><<<256, 512, 0, stream>>>(lstmF + 0L,      seq, ebih0, ebhh0, nullptr, Ya, hT0);
  // encoder L1 (only final h needed)
  k_scan<true><<<256, 512, 0, stream>>>(lstmF + 184320L, Ya, ebih1, ebhh1, nullptr, nullptr, hT1);
  // decoder L0 (zero input)
  k_scan<false><<<256, 512, 0, stream>>>(lstmF + 368640L, nullptr, dbih0, dbhh0, hT0, Yb, nullptr);
  // decoder L1
  k_scan<true><<<256, 512, 0, stream>>>(lstmF + 460800L, Yb, dbih1, dbhh1, hT1, Ya, nullptr);

  k_probs<<<1, 576, 0, stream>>>(nullptr, Ya, 12,
                                 gW3, gb3, ga3, 16, 4,
                                 gW4, gb4, ga4, 24, 6,
                                 M3f, 5, M4f, 6);
  k_tail<<<1536, 512, 0, stream>>>(Ya, M3f, gb3, M4f, gb4, fWt, fb, x, out);
}